// Round 15
// baseline (117.739 us; speedup 1.0000x reference)
//
#include <hip/hip_runtime.h>
#include <math.h>

#define HW    1024
#define CCH   256
#define NHEAD 8
#define HIDC  1024
#define BATCH 8
#define L2E   1.44269504f

typedef unsigned short u16;
typedef __attribute__((ext_vector_type(8))) short  bf16x8;
typedef __attribute__((ext_vector_type(4))) float  f32x4;
typedef __attribute__((ext_vector_type(8))) unsigned short us8;
typedef __attribute__((ext_vector_type(4))) unsigned short us4;

__device__ __forceinline__ u16 f2b(float f) {
    union { float f; unsigned u; } c; c.f = f;
    unsigned r = c.u + 0x7FFFu + ((c.u >> 16) & 1u);
    return (u16)(r >> 16);
}
__device__ __forceinline__ float b2f(u16 u) {
    union { unsigned u; float f; } c; c.u = ((unsigned)u) << 16;
    return c.f;
}
// NON-volatile: pure value op, let the scheduler reorder/CSE freely.
__device__ __forceinline__ unsigned cvt_pk_bf16(float a, float b) {
    unsigned r;
    asm("v_cvt_pk_bf16_f32 %0, %1, %2" : "=v"(r) : "v"(a), "v"(b));
    return r;
}
// single-instruction 2^x (OCML exp2f adds range/denorm fixup we don't need:
// attn scores bounded |x|<~50; gelu args bounded too).
__device__ __forceinline__ float fexp2(float x) {
    float r;
    asm("v_exp_f32 %0, %1" : "=v"(r) : "v"(x));
    return r;
}
__device__ __forceinline__ float frcp(float x) {
    float r;
    asm("v_rcp_f32 %0, %1" : "=v"(r) : "v"(x));
    return r;
}

// ---------------------------------------------------------------------------
// BN coefficients + temp-scale for Q: coef = [a1|be1|a2|be2|tsc]
// ---------------------------------------------------------------------------
__global__ void bn_coef_kernel(const float* __restrict__ g1, const float* __restrict__ b1,
                               const float* __restrict__ m1, const float* __restrict__ v1,
                               const float* __restrict__ g2, const float* __restrict__ b2,
                               const float* __restrict__ m2, const float* __restrict__ v2,
                               const float* __restrict__ temp, float* __restrict__ coef) {
    int c = threadIdx.x;
    if (c < CCH) {
        float i1 = g1[c] * rsqrtf(v1[c] + 1e-5f);
        coef[c]        = i1;
        coef[256 + c]  = b1[c] - m1[c] * i1;
        float i2 = g2[c] * rsqrtf(v2[c] + 1e-5f);
        coef[512 + c]  = i2;
        coef[768 + c]  = b2[c] - m2[c] * i2;
        coef[1024 + c] = temp[c >> 5] * L2E;
    }
}

// all six weight tensors -> bf16 (row-major [m][k], unchanged layout)
__global__ __launch_bounds__(256)
void cvt_all(const float* __restrict__ qw, const float* __restrict__ kw,
             const float* __restrict__ vw, const float* __restrict__ pw,
             const float* __restrict__ f1, const float* __restrict__ f2,
             u16* __restrict__ dst) {
    int bid = blockIdx.x;
    const float* src; size_t off; int lb;
    if      (bid < 64)  { src = qw; off = 0;      lb = bid; }
    else if (bid < 128) { src = kw; off = 65536;  lb = bid - 64; }
    else if (bid < 192) { src = vw; off = 131072; lb = bid - 128; }
    else if (bid < 256) { src = pw; off = 196608; lb = bid - 192; }
    else if (bid < 512) { src = f1; off = 262144; lb = bid - 256; }
    else                { src = f2; off = 524288; lb = bid - 512; }
    int i = lb * 1024 + threadIdx.x * 4;
    float4 v = *(const float4*)(src + i);
    us4 o = { f2b(v.x), f2b(v.y), f2b(v.z), f2b(v.w) };
    *(us4*)(dst + off + i) = o;
}

// depthwise weights transposed: dwt[t][c] = dw[c][t], bf16
__global__ __launch_bounds__(256)
void dwt_kernel(const float* __restrict__ dw, u16* __restrict__ dwt) {
    int idx = blockIdx.x * 256 + threadIdx.x;
    if (idx < 9 * HIDC) {
        int t = idx >> 10, c = idx & 1023;
        dwt[t * HIDC + c] = f2b(dw[c * 9 + t]);
    }
}

// ---------------------------------------------------------------------------
// x (NCHW fp32) -> bn1 -> bf16 NHWC [b][n][c], transposed via LDS tile 64x64
// ---------------------------------------------------------------------------
__global__ __launch_bounds__(256)
void xbn_t_kernel(const float* __restrict__ x1, const float* __restrict__ x2,
                  const float* __restrict__ a, const float* __restrict__ be,
                  u16* __restrict__ o1, u16* __restrict__ o2) {
    __shared__ alignas(16) u16 lt[64 * 72];
    int z = blockIdx.z;
    const float* x = (z & 1) ? x2 : x1;
    u16* o = (z & 1) ? o2 : o1;
    int b = z >> 1;
    int n0 = blockIdx.x * 64, c0 = blockIdx.y * 64;
    const float* xb = x + ((size_t)b * CCH + c0) * HW + n0;
    int tid = threadIdx.x;
    int row = tid >> 4, col4 = (tid & 15) * 4;
#pragma unroll
    for (int it = 0; it < 4; ++it) {
        int rr = it * 16 + row;
        float sc = a[c0 + rr], sh = be[c0 + rr];
        float4 v = *(const float4*)(xb + (size_t)rr * HW + col4);
        lt[(col4 + 0) * 72 + rr] = f2b(v.x * sc + sh);
        lt[(col4 + 1) * 72 + rr] = f2b(v.y * sc + sh);
        lt[(col4 + 2) * 72 + rr] = f2b(v.z * sc + sh);
        lt[(col4 + 3) * 72 + rr] = f2b(v.w * sc + sh);
    }
    __syncthreads();
    u16* ob = o + ((size_t)b * HW + n0) * CCH + c0;
#pragma unroll
    for (int rep = 0; rep < 2; ++rep) {
        int idx = tid * 2 + rep;
        int nl = idx >> 3, slot = idx & 7;
        us8 v = *(const us8*)(&lt[nl * 72 + slot * 8]);
        *(us8*)(ob + (size_t)nl * CCH + slot * 8) = v;
    }
}

// ---------------------------------------------------------------------------
// Shared staging: rule-21 gload_lds pair (linear LDS dest, inverse-swizzled
// source). Works for any wave id wv (region = wv*2+r spans 8 rows each).
// ---------------------------------------------------------------------------
__device__ __forceinline__ void stage_pair(const u16* Xb, const u16* Wb, int K, int koff,
                                           u16* lx, u16* lw, int wv, int lane) {
    int rl = lane >> 3, slot = lane & 7;
#pragma unroll
    for (int r = 0; r < 2; ++r) {
        int region = wv * 2 + r;
        int row = region * 8 + rl;
        int sw = ((slot ^ (row & 7)) << 3) + koff;
        __builtin_amdgcn_global_load_lds(
            (const __attribute__((address_space(1))) void*)(Xb + (size_t)row * K + sw),
            (__attribute__((address_space(3))) void*)(lx + (region << 9)), 16, 0, 0);
        __builtin_amdgcn_global_load_lds(
            (const __attribute__((address_space(1))) void*)(Wb + (size_t)row * K + sw),
            (__attribute__((address_space(3))) void*)(lw + (region << 9)), 16, 0, 0);
    }
}

__device__ __forceinline__ void compute_tile(const u16* lx, const u16* lw,
                                             int cc, int g, int wr, int wc,
                                             f32x4 acc[2][2]) {
#pragma unroll
    for (int ks = 0; ks < 2; ++ks) {
        bf16x8 ax[2], bw[2];
#pragma unroll
        for (int mi = 0; mi < 2; ++mi) {
            int row = wr * 32 + mi * 16 + cc;
            int ck = (ks * 4 + g) ^ (row & 7);
            ax[mi] = *(const bf16x8*)(lx + row * 64 + ck * 8);
        }
#pragma unroll
        for (int ni = 0; ni < 2; ++ni) {
            int row = wc * 32 + ni * 16 + cc;
            int ck = (ks * 4 + g) ^ (row & 7);
            bw[ni] = *(const bf16x8*)(lw + row * 64 + ck * 8);
        }
#pragma unroll
        for (int mi = 0; mi < 2; ++mi)
#pragma unroll
            for (int ni = 0; ni < 2; ++ni)
                acc[mi][ni] = __builtin_amdgcn_mfma_f32_16x16x32_bf16(
                    ax[mi], bw[ni], acc[mi][ni], 0, 0, 0);
    }
}

// 128x128-tile compute: 8 waves, wave tile 64(n) x 32(m): 4x2 fragments.
__device__ __forceinline__ void compute_tile128(const u16* lx, const u16* lw,
                                                int cc, int g, int wr, int wcq,
                                                f32x4 acc[4][2]) {
#pragma unroll
    for (int ks = 0; ks < 2; ++ks) {
        bf16x8 ax[4], bw[2];
#pragma unroll
        for (int mi = 0; mi < 4; ++mi) {
            int row = wr * 64 + mi * 16 + cc;
            int ck = (ks * 4 + g) ^ (row & 7);
            ax[mi] = *(const bf16x8*)(lx + row * 64 + ck * 8);
        }
#pragma unroll
        for (int ni = 0; ni < 2; ++ni) {
            int row = wcq * 32 + ni * 16 + cc;
            int ck = (ks * 4 + g) ^ (row & 7);
            bw[ni] = *(const bf16x8*)(lw + row * 64 + ck * 8);
        }
#pragma unroll
        for (int mi = 0; mi < 4; ++mi)
#pragma unroll
            for (int ni = 0; ni < 2; ++ni)
                acc[mi][ni] = __builtin_amdgcn_mfma_f32_16x16x32_bf16(
                    ax[mi], bw[ni], acc[mi][ni], 0, 0, 0);
    }
}

// ---------------------------------------------------------------------------
// Generic 64x64 GEMM (proj / fc2). X NHWC [b][HW][K]; W [M][K].
// outf/resid fp32 NCHW; outb bf16 NHWC (optional BN fold).
// ---------------------------------------------------------------------------
__global__ __launch_bounds__(256, 4)
void gemm_nhwc(const u16* __restrict__ W, const u16* __restrict__ X,
               const float* __restrict__ bias, const float* __restrict__ resid,
               float* __restrict__ outf, u16* __restrict__ outb,
               const float* __restrict__ bn_a, const float* __restrict__ bn_be,
               int K, int M) {
    __shared__ alignas(16) u16 lx[2][4096];
    __shared__ alignas(16) u16 lw[2][4096];
    const int tid = threadIdx.x, l = tid & 63, wv = tid >> 6;
    const int cc = l & 15, g = l >> 4;
    const int wr = wv >> 1, wc = wv & 1;
    const int n0 = blockIdx.x * 64, m0 = blockIdx.y * 64, b = blockIdx.z;
    const u16* Xb = X + ((size_t)b * HW + n0) * K;
    const u16* Wb = W + (size_t)m0 * K;
    const size_t bo = (size_t)b * M * HW;
    if (resid) resid += bo;
    if (outf)  outf  += bo;
    if (outb)  outb  += (size_t)b * HW * M;

    f32x4 acc[2][2];
    acc[0][0] = (f32x4)0.f; acc[0][1] = (f32x4)0.f;
    acc[1][0] = (f32x4)0.f; acc[1][1] = (f32x4)0.f;

    const int NT = K >> 6;
    stage_pair(Xb, Wb, K, 0, lx[0], lw[0], wv, l);
    __syncthreads();
    int cur = 0;
    for (int t = 0; t < NT; ++t) {
        if (t + 1 < NT)
            stage_pair(Xb, Wb, K, (t + 1) * 64, lx[cur ^ 1], lw[cur ^ 1], wv, l);
        compute_tile(lx[cur], lw[cur], cc, g, wr, wc, acc);
        __syncthreads();
        cur ^= 1;
    }

#pragma unroll
    for (int mi = 0; mi < 2; ++mi)
#pragma unroll
        for (int ni = 0; ni < 2; ++ni) {
            int m  = m0 + wc * 32 + ni * 16 + cc;
            int nb = n0 + wr * 32 + mi * 16 + g * 4;
            f32x4 v = acc[mi][ni];
            if (bias) { float bv = bias[m]; v[0] += bv; v[1] += bv; v[2] += bv; v[3] += bv; }
            if (resid) {
                float4 rv = *(const float4*)(resid + (size_t)m * HW + nb);
                v[0] += rv.x; v[1] += rv.y; v[2] += rv.z; v[3] += rv.w;
            }
            if (outf) *(f32x4*)(outf + (size_t)m * HW + nb) = v;
            if (outb) {
                float sa = bn_a ? bn_a[m] : 1.0f;
                float sb = bn_a ? bn_be[m] : 0.0f;
#pragma unroll
                for (int r = 0; r < 4; ++r)
                    outb[(size_t)(nb + r) * M + m] = f2b(v[r] * sa + sb);
            }
        }
}

// ---------------------------------------------------------------------------
// fc1: 128x128-tile GEMM (8 waves), bias + bf16 NHWC out. K=256, M=1024.
// ---------------------------------------------------------------------------
__global__ __launch_bounds__(512, 4)
void gemm128_nhwc(const u16* __restrict__ W, const u16* __restrict__ X,
                  const float* __restrict__ bias, u16* __restrict__ outb,
                  int K, int M) {
    __shared__ alignas(16) u16 lx[2][8192];
    __shared__ alignas(16) u16 lw[2][8192];
    const int tid = threadIdx.x, l = tid & 63, wv = tid >> 6;
    const int cc = l & 15, g = l >> 4;
    const int wr = wv >> 2, wcq = wv & 3;
    const int n0 = blockIdx.x * 128, m0 = blockIdx.y * 128, b = blockIdx.z;
    const u16* Xb = X + ((size_t)b * HW + n0) * K;
    const u16* Wb = W + (size_t)m0 * K;
    outb += (size_t)b * HW * M;

    f32x4 acc[4][2];
#pragma unroll
    for (int i = 0; i < 4; ++i) { acc[i][0] = (f32x4)0.f; acc[i][1] = (f32x4)0.f; }

    const int NT = K >> 6;
    stage_pair(Xb, Wb, K, 0, lx[0], lw[0], wv, l);
    __syncthreads();
    int cur = 0;
    for (int t = 0; t < NT; ++t) {
        if (t + 1 < NT)
            stage_pair(Xb, Wb, K, (t + 1) * 64, lx[cur ^ 1], lw[cur ^ 1], wv, l);
        compute_tile128(lx[cur], lw[cur], cc, g, wr, wcq, acc);
        __syncthreads();
        cur ^= 1;
    }

#pragma unroll
    for (int mi = 0; mi < 4; ++mi)
#pragma unroll
        for (int ni = 0; ni < 2; ++ni) {
            int m  = m0 + wcq * 32 + ni * 16 + cc;
            int nb = n0 + wr * 64 + mi * 16 + g * 4;
            float bv = bias[m];
#pragma unroll
            for (int r = 0; r < 4; ++r)
                outb[(size_t)(nb + r) * M + m] = f2b(acc[mi][ni][r] + bv);
        }
}

// ---------------------------------------------------------------------------
// QKV GEMM, 128x128 tiles, 8 waves. blockIdx.y 0..5: sel = y>>1 (0=Q,1=K,2=V),
// m0 = (y&1)*128. Q (scaled by temp*log2e) and K -> NHWC [b][n][256];
// V -> NCHW [b][c][n].
// ---------------------------------------------------------------------------
__global__ __launch_bounds__(512, 4)
void qkv_gemm128(const u16* __restrict__ wq, const u16* __restrict__ wk,
                 const u16* __restrict__ wv, const u16* __restrict__ x1n,
                 const u16* __restrict__ x2n, const float* __restrict__ tscale,
                 u16* __restrict__ qt, u16* __restrict__ kt, u16* __restrict__ vbuf) {
    __shared__ alignas(16) u16 lx[2][8192];
    __shared__ alignas(16) u16 lw[2][8192];
    const int tid = threadIdx.x, l = tid & 63, wvv = tid >> 6;
    const int cc = l & 15, g = l >> 4;
    const int wr = wvv >> 2, wcq = wvv & 3;
    const int sel = blockIdx.y >> 1;
    const int n0 = blockIdx.x * 128, m0 = (blockIdx.y & 1) * 128, b = blockIdx.z;
    const u16* W = (sel == 0) ? wq : (sel == 1) ? wk : wv;
    const u16* Xb = ((sel == 0) ? x1n : x2n) + ((size_t)b * HW + n0) * CCH;
    const u16* Wb = W + (size_t)m0 * CCH;

    f32x4 acc[4][2];
#pragma unroll
    for (int i = 0; i < 4; ++i) { acc[i][0] = (f32x4)0.f; acc[i][1] = (f32x4)0.f; }

    stage_pair(Xb, Wb, CCH, 0, lx[0], lw[0], wvv, l);
    __syncthreads();
    int cur = 0;
    for (int t = 0; t < 4; ++t) {
        if (t + 1 < 4)
            stage_pair(Xb, Wb, CCH, (t + 1) * 64, lx[cur ^ 1], lw[cur ^ 1], wvv, l);
        compute_tile128(lx[cur], lw[cur], cc, g, wr, wcq, acc);
        __syncthreads();
        cur ^= 1;
    }

    if (sel < 2) {
        u16* ob = ((sel == 0) ? qt : kt) + (size_t)b * HW * CCH;
#pragma unroll
        for (int mi = 0; mi < 4; ++mi)
#pragma unroll
            for (int ni = 0; ni < 2; ++ni) {
                int m  = m0 + wcq * 32 + ni * 16 + cc;
                int nb = n0 + wr * 64 + mi * 16 + g * 4;
                float sc = (sel == 0) ? tscale[m] : 1.0f;
#pragma unroll
                for (int r = 0; r < 4; ++r)
                    ob[(size_t)(nb + r) * CCH + m] = f2b(acc[mi][ni][r] * sc);
            }
    } else {
        u16* ob = vbuf + (size_t)b * CCH * HW;
#pragma unroll
        for (int mi = 0; mi < 4; ++mi)
#pragma unroll
            for (int ni = 0; ni < 2; ++ni) {
                int m  = m0 + wcq * 32 + ni * 16 + cc;
                int nb = n0 + wr * 64 + mi * 16 + g * 4;
                us4 ov = { f2b(acc[mi][ni][0]), f2b(acc[mi][ni][1]),
                           f2b(acc[mi][ni][2]), f2b(acc[mi][ni][3]) };
                *(us4*)(ob + (size_t)m * HW + nb) = ov;
            }
    }
}

// ---------------------------------------------------------------------------
// Flash attention, max-free softmax + raw v_exp. THIS ROUND: 128-thread
// blocks (2 waves x 32 q-rows, QBLK=64), grid 1024 -> 8 blocks/CU =
// 4 waves/SIMD (was 2). Per-wave instruction stream unchanged; pure TLP
// doubling to hide the L2/LDS/TRANS latency chain.
// ---------------------------------------------------------------------------
#define ATT_LOAD(K0, K1, K2, K3, V0, V1, V2, V3, T) do {                      \
    const int j0_ = (T) * 64;                                                 \
    K0 = *(const bf16x8*)(kb + (size_t)(j0_ +  0 + c) * CCH + g * 8);         \
    K1 = *(const bf16x8*)(kb + (size_t)(j0_ + 16 + c) * CCH + g * 8);         \
    K2 = *(const bf16x8*)(kb + (size_t)(j0_ + 32 + c) * CCH + g * 8);         \
    K3 = *(const bf16x8*)(kb + (size_t)(j0_ + 48 + c) * CCH + g * 8);         \
    V0 = *(const bf16x8*)(vb + (size_t)( 0 + c) * HW + j0_ +  0 + g * 8);     \
    V1 = *(const bf16x8*)(vb + (size_t)(16 + c) * HW + j0_ +  0 + g * 8);     \
    V2 = *(const bf16x8*)(vb + (size_t)( 0 + c) * HW + j0_ + 32 + g * 8);     \
    V3 = *(const bf16x8*)(vb + (size_t)(16 + c) * HW + j0_ + 32 + g * 8);     \
} while (0)

#define ATT_COMP(K0, K1, K2, K3, V0, V1, V2, V3) do {                         \
    f32x4 s0[4], s1[4];                                                       \
    __builtin_amdgcn_s_setprio(1);                                            \
    s0[0] = __builtin_amdgcn_mfma_f32_16x16x32_bf16(K0, qf0, (f32x4)0.f, 0, 0, 0); \
    s1[0] = __builtin_amdgcn_mfma_f32_16x16x32_bf16(K0, qf1, (f32x4)0.f, 0, 0, 0); \
    s0[1] = __builtin_amdgcn_mfma_f32_16x16x32_bf16(K1, qf0, (f32x4)0.f, 0, 0, 0); \
    s1[1] = __builtin_amdgcn_mfma_f32_16x16x32_bf16(K1, qf1, (f32x4)0.f, 0, 0, 0); \
    s0[2] = __builtin_amdgcn_mfma_f32_16x16x32_bf16(K2, qf0, (f32x4)0.f, 0, 0, 0); \
    s1[2] = __builtin_amdgcn_mfma_f32_16x16x32_bf16(K2, qf1, (f32x4)0.f, 0, 0, 0); \
    s0[3] = __builtin_amdgcn_mfma_f32_16x16x32_bf16(K3, qf0, (f32x4)0.f, 0, 0, 0); \
    s1[3] = __builtin_amdgcn_mfma_f32_16x16x32_bf16(K3, qf1, (f32x4)0.f, 0, 0, 0); \
    __builtin_amdgcn_s_setprio(0);                                            \
    float ps0 = 0.f, ps1 = 0.f;                                               \
    _Pragma("unroll")                                                         \
    for (int nj = 0; nj < 4; ++nj) {                                          \
        int ck = (2 * nj + (g >> 1)) ^ swz;                                   \
        float a0 = fexp2(s0[nj][0]), a1 = fexp2(s0[nj][1]);                   \
        float a2 = fexp2(s0[nj][2]), a3 = fexp2(s0[nj][3]);                   \
        ps0 += (a0 + a1) + (a2 + a3);                                         \
        uint2 pk0;                                                            \
        pk0.x = cvt_pk_bf16(a0, a1);                                          \
        pk0.y = cvt_pk_bf16(a2, a3);                                          \
        *(uint2*)(&P[c * 64 + ck * 8 + (g & 1) * 4]) = pk0;                   \
        float d0 = fexp2(s1[nj][0]), d1 = fexp2(s1[nj][1]);                   \
        float d2 = fexp2(s1[nj][2]), d3 = fexp2(s1[nj][3]);                   \
        ps1 += (d0 + d1) + (d2 + d3);                                         \
        uint2 pk1;                                                            \
        pk1.x = cvt_pk_bf16(d0, d1);                                          \
        pk1.y = cvt_pk_bf16(d2, d3);                                          \
        *(uint2*)(&P[(16 + c) * 64 + ck * 8 + (g & 1) * 4]) = pk1;            \
    }                                                                         \
    rl0 += ps0; rl1 += ps1;                                                   \
    __builtin_amdgcn_s_setprio(1);                                            \
    _Pragma("unroll")                                                         \
    for (int kj = 0; kj < 2; ++kj) {                                          \
        bf16x8 pf0 = *(const bf16x8*)(&P[c * 64 + ((kj * 4 + g) ^ swz) * 8]); \
        bf16x8 pf1 = *(const bf16x8*)(&P[(16 + c) * 64 + ((kj * 4 + g) ^ swz) * 8]); \
        o00 = __builtin_amdgcn_mfma_f32_16x16x32_bf16(pf0, (kj ? V2 : V0), o00, 0, 0, 0); \
        o01 = __builtin_amdgcn_mfma_f32_16x16x32_bf16(pf0, (kj ? V3 : V1), o01, 0, 0, 0); \
        o10 = __builtin_amdgcn_mfma_f32_16x16x32_bf16(pf1, (kj ? V2 : V0), o10, 0, 0, 0); \
        o11 = __builtin_amdgcn_mfma_f32_16x16x32_bf16(pf1, (kj ? V3 : V1), o11, 0, 0, 0); \
    }                                                                         \
    __builtin_amdgcn_s_setprio(0);                                            \
} while (0)

__global__ __launch_bounds__(128)
void attn_mfma(const u16* __restrict__ qt, const u16* __restrict__ kt,
               const u16* __restrict__ vv, u16* __restrict__ out) {
    __shared__ alignas(16) u16 lds[4096];   // 2 waves x 2KB P buffers
    const int tid = threadIdx.x, l = tid & 63, w = tid >> 6;
    const int c = l & 15, g = l >> 4;
    const int swz = (c & 7) ^ ((c & 8) >> 1);
    const int bh = blockIdx.x & 63, qx = blockIdx.x >> 6;   // qx 0..15
    const int b = bh >> 3, h = bh & 7;
    const int n0 = qx * 64;
    u16* P = lds + w * 2048;

    const u16* qb = qt + ((size_t)b * HW + n0 + w * 32) * CCH + h * 32;
    const u16* kb = kt + (size_t)b * HW * CCH + h * 32;
    const u16* vb = vv + ((size_t)b * CCH + h * 32) * HW;

    bf16x8 qf0 = *(const bf16x8*)(qb + (size_t)c * CCH + g * 8);
    bf16x8 qf1 = *(const bf16x8*)(qb + (size_t)(16 + c) * CCH + g * 8);

    float rl0 = 0.f, rl1 = 0.f;
    f32x4 o00 = (f32x4)0.f, o01 = (f32x4)0.f;
    f32x4 o10 = (f32x4)0.f, o11 = (f32x4)0.f;

    bf16x8 kA0, kA1, kA2, kA3, vA0, vA1, vA2, vA3;
    bf16x8 kB0, kB1, kB2, kB3, vB0, vB1, vB2, vB3;

    ATT_LOAD(kA0, kA1, kA2, kA3, vA0, vA1, vA2, vA3, 0);
#pragma unroll 1
    for (int t = 0; t < 16; t += 2) {
        ATT_LOAD(kB0, kB1, kB2, kB3, vB0, vB1, vB2, vB3, t + 1);
        ATT_COMP(kA0, kA1, kA2, kA3, vA0, vA1, vA2, vA3);
        if (t + 2 < 16)
            ATT_LOAD(kA0, kA1, kA2, kA3, vA0, vA1, vA2, vA3, t + 2);
        ATT_COMP(kB0, kB1, kB2, kB3, vB0, vB1, vB2, vB3);
    }

    rl0 += __shfl_xor(rl0, 16); rl0 += __shfl_xor(rl0, 32);
    rl1 += __shfl_xor(rl1, 16); rl1 += __shfl_xor(rl1, 32);
    float inv0 = 1.0f / rl0, inv1 = 1.0f / rl1;
    float invr0[4], invr1[4];
#pragma unroll
    for (int r = 0; r < 4; ++r) {
        int src = (l & 48) | (g * 4 + r);
        invr0[r] = __shfl(inv0, src);
        invr1[r] = __shfl(inv1, src);
    }
    // O staging to wave-private LDS (plain C++: aliasing keeps order)
#pragma unroll
    for (int r = 0; r < 4; ++r) {
        int row0 = g * 4 + r, row1 = 16 + g * 4 + r;
        P[row0 * 40 + c]      = f2b(o00[r] * invr0[r]);
        P[row0 * 40 + 16 + c] = f2b(o01[r] * invr0[r]);
        P[row1 * 40 + c]      = f2b(o10[r] * invr1[r]);
        P[row1 * 40 + 16 + c] = f2b(o11[r] * invr1[r]);
    }
#pragma unroll
    for (int rep = 0; rep < 2; ++rep) {
        int u = l * 2 + rep;
        int i = u >> 2, part = u & 3;
        us8 ov = *(const us8*)(&P[i * 40 + part * 8]);
        *(us8*)(out + ((size_t)b * HW + n0 + w * 32 + i) * CCH + h * 32 + part * 8) = ov;
    }
}

// ---------------------------------------------------------------------------
// Depthwise 3x3 (SAME) + tanh-form GELU via sigmoid. NHWC bf16, 8 ch/thread.
// ---------------------------------------------------------------------------
__global__ __launch_bounds__(256)
void dwgelu_nhwc(const u16* __restrict__ in, const u16* __restrict__ wt,
                 u16* __restrict__ out) {
    int gid = blockIdx.x * 256 + threadIdx.x;
    int c0 = (gid & 127) * 8;
    int sp = (gid >> 7) & 1023;
    int b  = gid >> 17;
    int y = sp >> 5, x = sp & 31;
    const u16* ip = in + (size_t)b * HW * HIDC;
    float acc[8] = {0.f, 0.f, 0.f, 0.f, 0.f, 0.f, 0.f, 0.f};
#pragma unroll
    for (int dy = -1; dy <= 1; ++dy) {
        int yy = y + dy;
        if ((unsigned)yy >= 32u) continue;
#pragma unroll
        for (int dx = -1; dx <= 1; ++dx) {
            int xx = x + dx;
            if ((unsigned)xx >= 32u) continue;
            us8 iv = *(const us8*)(ip + (size_t)(yy * 32 + xx) * HIDC + c0);
            us8 wv = *(const us8*)(wt + ((dy + 1) * 3 + dx + 1) * HIDC + c0);
#pragma unroll
            for (int e = 0; e < 8; ++e)
                acc[e] = fmaf(b2f(wv[e]), b2f(iv[e]), acc[e]);
        }
    }
    us8 o;
#pragma unroll
    for (int e = 0; e < 8; ++e) {
        float v  = acc[e];
        float p  = fmaf(v * v, 0.044715f, 1.0f);
        float ar = (-2.3021178f * v) * p;
        float ge = v * frcp(1.0f + fexp2(ar));
        o[e] = f2b(ge);
    }
    *(us8*)(out + (size_t)gid * 8) = o;
}

// ---------------------------------------------------------------------------
extern "C" void kernel_launch(void* const* d_in, const int* in_sizes, int n_in,
                              void* d_out, int out_size, void* d_ws, size_t ws_size,
                              hipStream_t stream) {
    const float* x1     = (const float*)d_in[0];
    const float* x2     = (const float*)d_in[1];
    const float* bn1_g  = (const float*)d_in[2];
    const float* bn1_b  = (const float*)d_in[3];
    const float* bn1_m  = (const float*)d_in[4];
    const float* bn1_v  = (const float*)d_in[5];
    const float* q_w    = (const float*)d_in[6];
    const float* k_w    = (const float*)d_in[7];
    const float* v_w    = (const float*)d_in[8];
    const float* temp   = (const float*)d_in[9];
    const float* proj_w = (const float*)d_in[10];
    const float* proj_b = (const float*)d_in[11];
    const float* bn2_g  = (const float*)d_in[12];
    const float* bn2_b  = (const float*)d_in[13];
    const float* bn2_m  = (const float*)d_in[14];
    const float* bn2_v  = (const float*)d_in[15];
    const float* fc1_w  = (const float*)d_in[16];
    const float* fc1_b  = (const float*)d_in[17];
    const float* dw_w   = (const float*)d_in[18];
    const float* fc2_w  = (const float*)d_in[19];
    const float* fc2_b  = (const float*)d_in[20];

    const size_t SZ = (size_t)BATCH * CCH * HW;   // 2,097,152 elems
    float* coef = (float*)d_ws;                    // 2048 f32 reserved
    u16*   bp   = (u16*)(coef + 2048);
    u16* qwb   = bp;
    u16* kwb   = bp + 65536;
    u16* vwb   = bp + 131072;
    u16* pjwb  = bp + 196608;
    u16* fc1wb = bp + 262144;
    u16* fc2wb = bp + 524288;
    u16* dwt   = bp + 786432;          // 9216, reserve 16384
    u16* act   = bp + 802816;
    u16* x1n   = act;                  // NHWC bf16
    u16* x2n   = act + SZ;
    u16* qtb   = act + 2 * SZ;         // NHWC
    u16* ktb   = act + 3 * SZ;         // NHWC
    u16* vbuf  = act + 4 * SZ;         // NCHW
    u16* attnb = act + 5 * SZ;         // NHWC
    float* y1  = (float*)(act + 6 * SZ);  // fp32 NCHW (2*SZ u16)
    u16* y1n   = act + 8 * SZ;         // NHWC
    u16* h1    = act + 9 * SZ;         // NHWC [b][hw][1024], 4*SZ
    u16* h2    = act + 13 * SZ;        // NHWC, 4*SZ

    bn_coef_kernel<<<1, 256, 0, stream>>>(bn1_g, bn1_b, bn1_m, bn1_v,
                                          bn2_g, bn2_b, bn2_m, bn2_v, temp, coef);
    cvt_all<<<768, 256, 0, stream>>>(q_w, k_w, v_w, proj_w, fc1_w, fc2_w, bp);
    dwt_kernel<<<36, 256, 0, stream>>>(dw_w, dwt);
    xbn_t_kernel<<<dim3(16, 4, 16), 256, 0, stream>>>(x1, x2, coef, coef + 256,
                                                      x1n, x2n);

    // q,k,v: 128x128 tiles, 8 waves (grid 384)
    qkv_gemm128<<<dim3(8, 6, BATCH), 512, 0, stream>>>(qwb, kwb, vwb, x1n, x2n,
                                                       coef + 1024, qtb, ktb, vbuf);

    attn_mfma<<<1024, 128, 0, stream>>>(qtb, ktb, vbuf, attnb);

    // y1 = x1 + proj(attn) (fp32 NCHW); y1n = bn2(y1) (bf16 NHWC)
    gemm_nhwc<<<dim3(16, 4, BATCH), 256, 0, stream>>>(pjwb, attnb, proj_b, x1,
                                                      y1, y1n, coef + 512, coef + 768,
                                                      CCH, CCH);
    // h1 = fc1(y1n) + b (bf16 NHWC): 128x128 tiles (grid 512)
    gemm128_nhwc<<<dim3(8, 8, BATCH), 512, 0, stream>>>(fc1wb, y1n, fc1_b, h1,
                                                        CCH, HIDC);
    // h2 = gelu(dw(h1))
    dwgelu_nhwc<<<(BATCH * HW * HIDC / 8) / 256, 256, 0, stream>>>(h1, dwt, h2);

    // out = y1 + fc2(h2) + b (fp32 NCHW)
    gemm_nhwc<<<dim3(16, 4, BATCH), 256, 0, stream>>>(fc2wb, h2, fc2_b, y1,
                                                      (float*)d_out, nullptr,
                                                      nullptr, nullptr, HIDC, CCH);
}

// Round 16
// 109.356 us; speedup vs baseline: 1.0767x; 1.0767x over previous
//
#include <hip/hip_runtime.h>
#include <math.h>

#define HW    1024
#define CCH   256
#define NHEAD 8
#define HIDC  1024
#define BATCH 8
#define L2E   1.44269504f

typedef unsigned short u16;
typedef __attribute__((ext_vector_type(8))) short  bf16x8;
typedef __attribute__((ext_vector_type(4))) float  f32x4;
typedef __attribute__((ext_vector_type(8))) unsigned short us8;
typedef __attribute__((ext_vector_type(4))) unsigned short us4;

__device__ __forceinline__ u16 f2b(float f) {
    union { float f; unsigned u; } c; c.f = f;
    unsigned r = c.u + 0x7FFFu + ((c.u >> 16) & 1u);
    return (u16)(r >> 16);
}
__device__ __forceinline__ float b2f(u16 u) {
    union { unsigned u; float f; } c; c.u = ((unsigned)u) << 16;
    return c.f;
}
// NON-volatile pure value ops: scheduler may reorder/CSE.
__device__ __forceinline__ unsigned cvt_pk_bf16(float a, float b) {
    unsigned r;
    asm("v_cvt_pk_bf16_f32 %0, %1, %2" : "=v"(r) : "v"(a), "v"(b));
    return r;
}
__device__ __forceinline__ float fexp2(float x) {
    float r;
    asm("v_exp_f32 %0, %1" : "=v"(r) : "v"(x));
    return r;
}
__device__ __forceinline__ float frcp(float x) {
    float r;
    asm("v_rcp_f32 %0, %1" : "=v"(r) : "v"(x));
    return r;
}

// ---------------------------------------------------------------------------
// Weights -> bf16 + depthwise-weight transpose, ONE launch (launch fusion).
// bid<768: the six GEMM weights. bid>=768: dwt[t][c] = dw[c][t].
// ---------------------------------------------------------------------------
__global__ __launch_bounds__(256)
void cvt_all(const float* __restrict__ qw, const float* __restrict__ kw,
             const float* __restrict__ vw, const float* __restrict__ pw,
             const float* __restrict__ f1, const float* __restrict__ f2,
             const float* __restrict__ dw, u16* __restrict__ dst,
             u16* __restrict__ dwt) {
    int bid = blockIdx.x;
    if (bid >= 768) {
        int idx = (bid - 768) * 256 + threadIdx.x;
        if (idx < 9 * HIDC) {
            int t = idx >> 10, c = idx & 1023;
            dwt[t * HIDC + c] = f2b(dw[c * 9 + t]);
        }
        return;
    }
    const float* src; size_t off; int lb;
    if      (bid < 64)  { src = qw; off = 0;      lb = bid; }
    else if (bid < 128) { src = kw; off = 65536;  lb = bid - 64; }
    else if (bid < 192) { src = vw; off = 131072; lb = bid - 128; }
    else if (bid < 256) { src = pw; off = 196608; lb = bid - 192; }
    else if (bid < 512) { src = f1; off = 262144; lb = bid - 256; }
    else                { src = f2; off = 524288; lb = bid - 512; }
    int i = lb * 1024 + threadIdx.x * 4;
    float4 v = *(const float4*)(src + i);
    us4 o = { f2b(v.x), f2b(v.y), f2b(v.z), f2b(v.w) };
    *(us4*)(dst + off + i) = o;
}

// ---------------------------------------------------------------------------
// x (NCHW fp32) -> bn1 -> bf16 NHWC, transposed via LDS tile; bn1 coefs
// computed INLINE per block (few rsqrt, hidden) -- no bn_coef kernel.
// ---------------------------------------------------------------------------
__global__ __launch_bounds__(256)
void xbn_t_kernel(const float* __restrict__ x1, const float* __restrict__ x2,
                  const float* __restrict__ g1, const float* __restrict__ b1,
                  const float* __restrict__ m1, const float* __restrict__ v1,
                  u16* __restrict__ o1, u16* __restrict__ o2) {
    __shared__ alignas(16) u16 lt[64 * 72];
    int z = blockIdx.z;
    const float* x = (z & 1) ? x2 : x1;
    u16* o = (z & 1) ? o2 : o1;
    int b = z >> 1;
    int n0 = blockIdx.x * 64, c0 = blockIdx.y * 64;
    const float* xb = x + ((size_t)b * CCH + c0) * HW + n0;
    int tid = threadIdx.x;
    int row = tid >> 4, col4 = (tid & 15) * 4;
#pragma unroll
    for (int it = 0; it < 4; ++it) {
        int rr = it * 16 + row;
        int cch = c0 + rr;
        float sc = g1[cch] * rsqrtf(v1[cch] + 1e-5f);
        float sh = b1[cch] - m1[cch] * sc;
        float4 v = *(const float4*)(xb + (size_t)rr * HW + col4);
        lt[(col4 + 0) * 72 + rr] = f2b(v.x * sc + sh);
        lt[(col4 + 1) * 72 + rr] = f2b(v.y * sc + sh);
        lt[(col4 + 2) * 72 + rr] = f2b(v.z * sc + sh);
        lt[(col4 + 3) * 72 + rr] = f2b(v.w * sc + sh);
    }
    __syncthreads();
    u16* ob = o + ((size_t)b * HW + n0) * CCH + c0;
#pragma unroll
    for (int rep = 0; rep < 2; ++rep) {
        int idx = tid * 2 + rep;
        int nl = idx >> 3, slot = idx & 7;
        us8 v = *(const us8*)(&lt[nl * 72 + slot * 8]);
        *(us8*)(ob + (size_t)nl * CCH + slot * 8) = v;
    }
}

// ---------------------------------------------------------------------------
// Shared staging: rule-21 gload_lds pair (linear LDS dest, inverse-swizzled
// source). Works for any wave id wv (region = wv*2+r spans 8 rows each).
// ---------------------------------------------------------------------------
__device__ __forceinline__ void stage_pair(const u16* Xb, const u16* Wb, int K, int koff,
                                           u16* lx, u16* lw, int wv, int lane) {
    int rl = lane >> 3, slot = lane & 7;
#pragma unroll
    for (int r = 0; r < 2; ++r) {
        int region = wv * 2 + r;
        int row = region * 8 + rl;
        int sw = ((slot ^ (row & 7)) << 3) + koff;
        __builtin_amdgcn_global_load_lds(
            (const __attribute__((address_space(1))) void*)(Xb + (size_t)row * K + sw),
            (__attribute__((address_space(3))) void*)(lx + (region << 9)), 16, 0, 0);
        __builtin_amdgcn_global_load_lds(
            (const __attribute__((address_space(1))) void*)(Wb + (size_t)row * K + sw),
            (__attribute__((address_space(3))) void*)(lw + (region << 9)), 16, 0, 0);
    }
}

__device__ __forceinline__ void compute_tile(const u16* lx, const u16* lw,
                                             int cc, int g, int wr, int wc,
                                             f32x4 acc[2][2]) {
#pragma unroll
    for (int ks = 0; ks < 2; ++ks) {
        bf16x8 ax[2], bw[2];
#pragma unroll
        for (int mi = 0; mi < 2; ++mi) {
            int row = wr * 32 + mi * 16 + cc;
            int ck = (ks * 4 + g) ^ (row & 7);
            ax[mi] = *(const bf16x8*)(lx + row * 64 + ck * 8);
        }
#pragma unroll
        for (int ni = 0; ni < 2; ++ni) {
            int row = wc * 32 + ni * 16 + cc;
            int ck = (ks * 4 + g) ^ (row & 7);
            bw[ni] = *(const bf16x8*)(lw + row * 64 + ck * 8);
        }
#pragma unroll
        for (int mi = 0; mi < 2; ++mi)
#pragma unroll
            for (int ni = 0; ni < 2; ++ni)
                acc[mi][ni] = __builtin_amdgcn_mfma_f32_16x16x32_bf16(
                    ax[mi], bw[ni], acc[mi][ni], 0, 0, 0);
    }
}

// 128x128-tile compute: 8 waves, wave tile 64(n) x 32(m): 4x2 fragments.
__device__ __forceinline__ void compute_tile128(const u16* lx, const u16* lw,
                                                int cc, int g, int wr, int wcq,
                                                f32x4 acc[4][2]) {
#pragma unroll
    for (int ks = 0; ks < 2; ++ks) {
        bf16x8 ax[4], bw[2];
#pragma unroll
        for (int mi = 0; mi < 4; ++mi) {
            int row = wr * 64 + mi * 16 + cc;
            int ck = (ks * 4 + g) ^ (row & 7);
            ax[mi] = *(const bf16x8*)(lx + row * 64 + ck * 8);
        }
#pragma unroll
        for (int ni = 0; ni < 2; ++ni) {
            int row = wcq * 32 + ni * 16 + cc;
            int ck = (ks * 4 + g) ^ (row & 7);
            bw[ni] = *(const bf16x8*)(lw + row * 64 + ck * 8);
        }
#pragma unroll
        for (int mi = 0; mi < 4; ++mi)
#pragma unroll
            for (int ni = 0; ni < 2; ++ni)
                acc[mi][ni] = __builtin_amdgcn_mfma_f32_16x16x32_bf16(
                    ax[mi], bw[ni], acc[mi][ni], 0, 0, 0);
    }
}

// ---------------------------------------------------------------------------
// Generic 64x64 GEMM (proj / fc2). X NHWC [b][HW][K]; W [M][K].
// outf/resid fp32 NCHW; outb bf16 NHWC. BN2 coefs (for proj's y1n output)
// computed INLINE from raw params (2 rsqrt/thread, hidden).
// ---------------------------------------------------------------------------
__global__ __launch_bounds__(256, 4)
void gemm_nhwc(const u16* __restrict__ W, const u16* __restrict__ X,
               const float* __restrict__ bias, const float* __restrict__ resid,
               float* __restrict__ outf, u16* __restrict__ outb,
               const float* __restrict__ bn_g, const float* __restrict__ bn_b,
               const float* __restrict__ bn_m, const float* __restrict__ bn_v,
               int K, int M) {
    __shared__ alignas(16) u16 lx[2][4096];
    __shared__ alignas(16) u16 lw[2][4096];
    const int tid = threadIdx.x, l = tid & 63, wv = tid >> 6;
    const int cc = l & 15, g = l >> 4;
    const int wr = wv >> 1, wc = wv & 1;
    const int n0 = blockIdx.x * 64, m0 = blockIdx.y * 64, b = blockIdx.z;
    const u16* Xb = X + ((size_t)b * HW + n0) * K;
    const u16* Wb = W + (size_t)m0 * K;
    const size_t bo = (size_t)b * M * HW;
    if (resid) resid += bo;
    if (outf)  outf  += bo;
    if (outb)  outb  += (size_t)b * HW * M;

    f32x4 acc[2][2];
    acc[0][0] = (f32x4)0.f; acc[0][1] = (f32x4)0.f;
    acc[1][0] = (f32x4)0.f; acc[1][1] = (f32x4)0.f;

    const int NT = K >> 6;
    stage_pair(Xb, Wb, K, 0, lx[0], lw[0], wv, l);
    __syncthreads();
    int cur = 0;
    for (int t = 0; t < NT; ++t) {
        if (t + 1 < NT)
            stage_pair(Xb, Wb, K, (t + 1) * 64, lx[cur ^ 1], lw[cur ^ 1], wv, l);
        compute_tile(lx[cur], lw[cur], cc, g, wr, wc, acc);
        __syncthreads();
        cur ^= 1;
    }

#pragma unroll
    for (int mi = 0; mi < 2; ++mi)
#pragma unroll
        for (int ni = 0; ni < 2; ++ni) {
            int m  = m0 + wc * 32 + ni * 16 + cc;
            int nb = n0 + wr * 32 + mi * 16 + g * 4;
            f32x4 v = acc[mi][ni];
            if (bias) { float bv = bias[m]; v[0] += bv; v[1] += bv; v[2] += bv; v[3] += bv; }
            if (resid) {
                float4 rv = *(const float4*)(resid + (size_t)m * HW + nb);
                v[0] += rv.x; v[1] += rv.y; v[2] += rv.z; v[3] += rv.w;
            }
            if (outf) *(f32x4*)(outf + (size_t)m * HW + nb) = v;
            if (outb) {
                float sa = 1.0f, sb = 0.0f;
                if (bn_g) {
                    sa = bn_g[m] * rsqrtf(bn_v[m] + 1e-5f);
                    sb = bn_b[m] - bn_m[m] * sa;
                }
#pragma unroll
                for (int r = 0; r < 4; ++r)
                    outb[(size_t)(nb + r) * M + m] = f2b(v[r] * sa + sb);
            }
        }
}

// ---------------------------------------------------------------------------
// fc1: 128x128-tile GEMM (8 waves), bias + bf16 NHWC out. K=256, M=1024.
// ---------------------------------------------------------------------------
__global__ __launch_bounds__(512, 4)
void gemm128_nhwc(const u16* __restrict__ W, const u16* __restrict__ X,
                  const float* __restrict__ bias, u16* __restrict__ outb,
                  int K, int M) {
    __shared__ alignas(16) u16 lx[2][8192];
    __shared__ alignas(16) u16 lw[2][8192];
    const int tid = threadIdx.x, l = tid & 63, wv = tid >> 6;
    const int cc = l & 15, g = l >> 4;
    const int wr = wv >> 2, wcq = wv & 3;
    const int n0 = blockIdx.x * 128, m0 = blockIdx.y * 128, b = blockIdx.z;
    const u16* Xb = X + ((size_t)b * HW + n0) * K;
    const u16* Wb = W + (size_t)m0 * K;
    outb += (size_t)b * HW * M;

    f32x4 acc[4][2];
#pragma unroll
    for (int i = 0; i < 4; ++i) { acc[i][0] = (f32x4)0.f; acc[i][1] = (f32x4)0.f; }

    const int NT = K >> 6;
    stage_pair(Xb, Wb, K, 0, lx[0], lw[0], wv, l);
    __syncthreads();
    int cur = 0;
    for (int t = 0; t < NT; ++t) {
        if (t + 1 < NT)
            stage_pair(Xb, Wb, K, (t + 1) * 64, lx[cur ^ 1], lw[cur ^ 1], wv, l);
        compute_tile128(lx[cur], lw[cur], cc, g, wr, wcq, acc);
        __syncthreads();
        cur ^= 1;
    }

#pragma unroll
    for (int mi = 0; mi < 4; ++mi)
#pragma unroll
        for (int ni = 0; ni < 2; ++ni) {
            int m  = m0 + wcq * 32 + ni * 16 + cc;
            int nb = n0 + wr * 64 + mi * 16 + g * 4;
            float bv = bias[m];
#pragma unroll
            for (int r = 0; r < 4; ++r)
                outb[(size_t)(nb + r) * M + m] = f2b(acc[mi][ni][r] + bv);
        }
}

// ---------------------------------------------------------------------------
// QKV GEMM, 128x128 tiles, 8 waves. sel = y>>1 (0=Q,1=K,2=V), m0=(y&1)*128.
// Q scaled inline by temp[m>>5]*log2e (no precomputed tscale). Q,K -> NHWC;
// V -> NCHW.
// ---------------------------------------------------------------------------
__global__ __launch_bounds__(512, 4)
void qkv_gemm128(const u16* __restrict__ wq, const u16* __restrict__ wk,
                 const u16* __restrict__ wv, const u16* __restrict__ x1n,
                 const u16* __restrict__ x2n, const float* __restrict__ temp,
                 u16* __restrict__ qt, u16* __restrict__ kt, u16* __restrict__ vbuf) {
    __shared__ alignas(16) u16 lx[2][8192];
    __shared__ alignas(16) u16 lw[2][8192];
    const int tid = threadIdx.x, l = tid & 63, wvv = tid >> 6;
    const int cc = l & 15, g = l >> 4;
    const int wr = wvv >> 2, wcq = wvv & 3;
    const int sel = blockIdx.y >> 1;
    const int n0 = blockIdx.x * 128, m0 = (blockIdx.y & 1) * 128, b = blockIdx.z;
    const u16* W = (sel == 0) ? wq : (sel == 1) ? wk : wv;
    const u16* Xb = ((sel == 0) ? x1n : x2n) + ((size_t)b * HW + n0) * CCH;
    const u16* Wb = W + (size_t)m0 * CCH;

    f32x4 acc[4][2];
#pragma unroll
    for (int i = 0; i < 4; ++i) { acc[i][0] = (f32x4)0.f; acc[i][1] = (f32x4)0.f; }

    stage_pair(Xb, Wb, CCH, 0, lx[0], lw[0], wvv, l);
    __syncthreads();
    int cur = 0;
    for (int t = 0; t < 4; ++t) {
        if (t + 1 < 4)
            stage_pair(Xb, Wb, CCH, (t + 1) * 64, lx[cur ^ 1], lw[cur ^ 1], wvv, l);
        compute_tile128(lx[cur], lw[cur], cc, g, wr, wcq, acc);
        __syncthreads();
        cur ^= 1;
    }

    if (sel < 2) {
        u16* ob = ((sel == 0) ? qt : kt) + (size_t)b * HW * CCH;
#pragma unroll
        for (int mi = 0; mi < 4; ++mi)
#pragma unroll
            for (int ni = 0; ni < 2; ++ni) {
                int m  = m0 + wcq * 32 + ni * 16 + cc;
                int nb = n0 + wr * 64 + mi * 16 + g * 4;
                float sc = (sel == 0) ? temp[m >> 5] * L2E : 1.0f;
#pragma unroll
                for (int r = 0; r < 4; ++r)
                    ob[(size_t)(nb + r) * CCH + m] = f2b(acc[mi][ni][r] * sc);
            }
    } else {
        u16* ob = vbuf + (size_t)b * CCH * HW;
#pragma unroll
        for (int mi = 0; mi < 4; ++mi)
#pragma unroll
            for (int ni = 0; ni < 2; ++ni) {
                int m  = m0 + wcq * 32 + ni * 16 + cc;
                int nb = n0 + wr * 64 + mi * 16 + g * 4;
                us4 ov = { f2b(acc[mi][ni][0]), f2b(acc[mi][ni][1]),
                           f2b(acc[mi][ni][2]), f2b(acc[mi][ni][3]) };
                *(us4*)(ob + (size_t)m * HW + nb) = ov;
            }
    }
}

// ---------------------------------------------------------------------------
// Flash attention (r14 config -- converged): max-free softmax, raw v_exp,
// 256-thread blocks (4 waves x 32 q-rows, QBLK=128), grid 512 XCD-local.
// ---------------------------------------------------------------------------
#define ATT_LOAD(K0, K1, K2, K3, V0, V1, V2, V3, T) do {                      \
    const int j0_ = (T) * 64;                                                 \
    K0 = *(const bf16x8*)(kb + (size_t)(j0_ +  0 + c) * CCH + g * 8);         \
    K1 = *(const bf16x8*)(kb + (size_t)(j0_ + 16 + c) * CCH + g * 8);         \
    K2 = *(const bf16x8*)(kb + (size_t)(j0_ + 32 + c) * CCH + g * 8);         \
    K3 = *(const bf16x8*)(kb + (size_t)(j0_ + 48 + c) * CCH + g * 8);         \
    V0 = *(const bf16x8*)(vb + (size_t)( 0 + c) * HW + j0_ +  0 + g * 8);     \
    V1 = *(const bf16x8*)(vb + (size_t)(16 + c) * HW + j0_ +  0 + g * 8);     \
    V2 = *(const bf16x8*)(vb + (size_t)( 0 + c) * HW + j0_ + 32 + g * 8);     \
    V3 = *(const bf16x8*)(vb + (size_t)(16 + c) * HW + j0_ + 32 + g * 8);     \
} while (0)

#define ATT_COMP(K0, K1, K2, K3, V0, V1, V2, V3) do {                         \
    f32x4 s0[4], s1[4];                                                       \
    __builtin_amdgcn_s_setprio(1);                                            \
    s0[0] = __builtin_amdgcn_mfma_f32_16x16x32_bf16(K0, qf0, (f32x4)0.f, 0, 0, 0); \
    s1[0] = __builtin_amdgcn_mfma_f32_16x16x32_bf16(K0, qf1, (f32x4)0.f, 0, 0, 0); \
    s0[1] = __builtin_amdgcn_mfma_f32_16x16x32_bf16(K1, qf0, (f32x4)0.f, 0, 0, 0); \
    s1[1] = __builtin_amdgcn_mfma_f32_16x16x32_bf16(K1, qf1, (f32x4)0.f, 0, 0, 0); \
    s0[2] = __builtin_amdgcn_mfma_f32_16x16x32_bf16(K2, qf0, (f32x4)0.f, 0, 0, 0); \
    s1[2] = __builtin_amdgcn_mfma_f32_16x16x32_bf16(K2, qf1, (f32x4)0.f, 0, 0, 0); \
    s0[3] = __builtin_amdgcn_mfma_f32_16x16x32_bf16(K3, qf0, (f32x4)0.f, 0, 0, 0); \
    s1[3] = __builtin_amdgcn_mfma_f32_16x16x32_bf16(K3, qf1, (f32x4)0.f, 0, 0, 0); \
    __builtin_amdgcn_s_setprio(0);                                            \
    float ps0 = 0.f, ps1 = 0.f;                                               \
    _Pragma("unroll")                                                         \
    for (int nj = 0; nj < 4; ++nj) {                                          \
        int ck = (2 * nj + (g >> 1)) ^ swz;                                   \
        float a0 = fexp2(s0[nj][0]), a1 = fexp2(s0[nj][1]);                   \
        float a2 = fexp2(s0[nj][2]), a3 = fexp2(s0[nj][3]);                   \
        ps0 += (a0 + a1) + (a2 + a3);                                         \
        uint2 pk0;                                                            \
        pk0.x = cvt_pk_bf16(a0, a1);                                          \
        pk0.y = cvt_pk_bf16(a2, a3);                                          \
        *(uint2*)(&P[c * 64 + ck * 8 + (g & 1) * 4]) = pk0;                   \
        float d0 = fexp2(s1[nj][0]), d1 = fexp2(s1[nj][1]);                   \
        float d2 = fexp2(s1[nj][2]), d3 = fexp2(s1[nj][3]);                   \
        ps1 += (d0 + d1) + (d2 + d3);                                         \
        uint2 pk1;                                                            \
        pk1.x = cvt_pk_bf16(d0, d1);                                          \
        pk1.y = cvt_pk_bf16(d2, d3);                                          \
        *(uint2*)(&P[(16 + c) * 64 + ck * 8 + (g & 1) * 4]) = pk1;            \
    }                                                                         \
    rl0 += ps0; rl1 += ps1;                                                   \
    __builtin_amdgcn_s_setprio(1);                                            \
    _Pragma("unroll")                                                         \
    for (int kj = 0; kj < 2; ++kj) {                                          \
        bf16x8 pf0 = *(const bf16x8*)(&P[c * 64 + ((kj * 4 + g) ^ swz) * 8]); \
        bf16x8 pf1 = *(const bf16x8*)(&P[(16 + c) * 64 + ((kj * 4 + g) ^ swz) * 8]); \
        o00 = __builtin_amdgcn_mfma_f32_16x16x32_bf16(pf0, (kj ? V2 : V0), o00, 0, 0, 0); \
        o01 = __builtin_amdgcn_mfma_f32_16x16x32_bf16(pf0, (kj ? V3 : V1), o01, 0, 0, 0); \
        o10 = __builtin_amdgcn_mfma_f32_16x16x32_bf16(pf1, (kj ? V2 : V0), o10, 0, 0, 0); \
        o11 = __builtin_amdgcn_mfma_f32_16x16x32_bf16(pf1, (kj ? V3 : V1), o11, 0, 0, 0); \
    }                                                                         \
    __builtin_amdgcn_s_setprio(0);                                            \
} while (0)

__global__ __launch_bounds__(256)
void attn_mfma(const u16* __restrict__ qt, const u16* __restrict__ kt,
               const u16* __restrict__ vv, u16* __restrict__ out) {
    __shared__ alignas(16) u16 lds[8192];   // 4 waves x 2KB P buffers
    const int tid = threadIdx.x, l = tid & 63, w = tid >> 6;
    const int c = l & 15, g = l >> 4;
    const int swz = (c & 7) ^ ((c & 8) >> 1);
    const int bh = blockIdx.x & 63, qx = blockIdx.x >> 6;
    const int b = bh >> 3, h = bh & 7;
    const int n0 = qx * 128;
    u16* P = lds + w * 2048;

    const u16* qb = qt + ((size_t)b * HW + n0 + w * 32) * CCH + h * 32;
    const u16* kb = kt + (size_t)b * HW * CCH + h * 32;
    const u16* vb = vv + ((size_t)b * CCH + h * 32) * HW;

    bf16x8 qf0 = *(const bf16x8*)(qb + (size_t)c * CCH + g * 8);
    bf16x8 qf1 = *(const bf16x8*)(qb + (size_t)(16 + c) * CCH + g * 8);

    float rl0 = 0.f, rl1 = 0.f;
    f32x4 o00 = (f32x4)0.f, o01 = (f32x4)0.f;
    f32x4 o10 = (f32x4)0.f, o11 = (f32x4)0.f;

    bf16x8 kA0, kA1, kA2, kA3, vA0, vA1, vA2, vA3;
    bf16x8 kB0, kB1, kB2, kB3, vB0, vB1, vB2, vB3;

    ATT_LOAD(kA0, kA1, kA2, kA3, vA0, vA1, vA2, vA3, 0);
#pragma unroll 1
    for (int t = 0; t < 16; t += 2) {
        ATT_LOAD(kB0, kB1, kB2, kB3, vB0, vB1, vB2, vB3, t + 1);
        ATT_COMP(kA0, kA1, kA2, kA3, vA0, vA1, vA2, vA3);
        if (t + 2 < 16)
            ATT_LOAD(kA0, kA1, kA2, kA3, vA0, vA1, vA2, vA3, t + 2);
        ATT_COMP(kB0, kB1, kB2, kB3, vB0, vB1, vB2, vB3);
    }

    rl0 += __shfl_xor(rl0, 16); rl0 += __shfl_xor(rl0, 32);
    rl1 += __shfl_xor(rl1, 16); rl1 += __shfl_xor(rl1, 32);
    float inv0 = 1.0f / rl0, inv1 = 1.0f / rl1;
    float invr0[4], invr1[4];
#pragma unroll
    for (int r = 0; r < 4; ++r) {
        int src = (l & 48) | (g * 4 + r);
        invr0[r] = __shfl(inv0, src);
        invr1[r] = __shfl(inv1, src);
    }
    // O staging to wave-private LDS (plain C++: aliasing keeps order)
#pragma unroll
    for (int r = 0; r < 4; ++r) {
        int row0 = g * 4 + r, row1 = 16 + g * 4 + r;
        P[row0 * 40 + c]      = f2b(o00[r] * invr0[r]);
        P[row0 * 40 + 16 + c] = f2b(o01[r] * invr0[r]);
        P[row1 * 40 + c]      = f2b(o10[r] * invr1[r]);
        P[row1 * 40 + 16 + c] = f2b(o11[r] * invr1[r]);
    }
#pragma unroll
    for (int rep = 0; rep < 2; ++rep) {
        int u = l * 2 + rep;
        int i = u >> 2, part = u & 3;
        us8 ov = *(const us8*)(&P[i * 40 + part * 8]);
        *(us8*)(out + ((size_t)b * HW + n0 + w * 32 + i) * CCH + h * 32 + part * 8) = ov;
    }
}

// ---------------------------------------------------------------------------
// Depthwise 3x3 (SAME) + tanh-form GELU via sigmoid. NHWC bf16, 8 ch/thread.
// ---------------------------------------------------------------------------
__global__ __launch_bounds__(256)
void dwgelu_nhwc(const u16* __restrict__ in, const u16* __restrict__ wt,
                 u16* __restrict__ out) {
    int gid = blockIdx.x * 256 + threadIdx.x;
    int c0 = (gid & 127) * 8;
    int sp = (gid >> 7) & 1023;
    int b  = gid >> 17;
    int y = sp >> 5, x = sp & 31;
    const u16* ip = in + (size_t)b * HW * HIDC;
    float acc[8] = {0.f, 0.f, 0.f, 0.f, 0.f, 0.f, 0.f, 0.f};
#pragma unroll
    for (int dy = -1; dy <= 1; ++dy) {
        int yy = y + dy;
        if ((unsigned)yy >= 32u) continue;
#pragma unroll
        for (int dx = -1; dx <= 1; ++dx) {
            int xx = x + dx;
            if ((unsigned)xx >= 32u) continue;
            us8 iv = *(const us8*)(ip + (size_t)(yy * 32 + xx) * HIDC + c0);
            us8 wv = *(const us8*)(wt + ((dy + 1) * 3 + dx + 1) * HIDC + c0);
#pragma unroll
            for (int e = 0; e < 8; ++e)
                acc[e] = fmaf(b2f(wv[e]), b2f(iv[e]), acc[e]);
        }
    }
    us8 o;
#pragma unroll
    for (int e = 0; e < 8; ++e) {
        float v  = acc[e];
        float p  = fmaf(v * v, 0.044715f, 1.0f);
        float ar = (-2.3021178f * v) * p;
        float ge = v * frcp(1.0f + fexp2(ar));
        o[e] = f2b(ge);
    }
    *(us8*)(out + (size_t)gid * 8) = o;
}

// ---------------------------------------------------------------------------
extern "C" void kernel_launch(void* const* d_in, const int* in_sizes, int n_in,
                              void* d_out, int out_size, void* d_ws, size_t ws_size,
                              hipStream_t stream) {
    const float* x1     = (const float*)d_in[0];
    const float* x2     = (const float*)d_in[1];
    const float* bn1_g  = (const float*)d_in[2];
    const float* bn1_b  = (const float*)d_in[3];
    const float* bn1_m  = (const float*)d_in[4];
    const float* bn1_v  = (const float*)d_in[5];
    const float* q_w    = (const float*)d_in[6];
    const float* k_w    = (const float*)d_in[7];
    const float* v_w    = (const float*)d_in[8];
    const float* temp   = (const float*)d_in[9];
    const float* proj_w = (const float*)d_in[10];
    const float* proj_b = (const float*)d_in[11];
    const float* bn2_g  = (const float*)d_in[12];
    const float* bn2_b  = (const float*)d_in[13];
    const float* bn2_m  = (const float*)d_in[14];
    const float* bn2_v  = (const float*)d_in[15];
    const float* fc1_w  = (const float*)d_in[16];
    const float* fc1_b  = (const float*)d_in[17];
    const float* dw_w   = (const float*)d_in[18];
    const float* fc2_w  = (const float*)d_in[19];
    const float* fc2_b  = (const float*)d_in[20];

    const size_t SZ = (size_t)BATCH * CCH * HW;   // 2,097,152 elems
    u16* bp    = (u16*)d_ws;
    u16* qwb   = bp;
    u16* kwb   = bp + 65536;
    u16* vwb   = bp + 131072;
    u16* pjwb  = bp + 196608;
    u16* fc1wb = bp + 262144;
    u16* fc2wb = bp + 524288;
    u16* dwt   = bp + 786432;          // 9216, reserve 16384
    u16* act   = bp + 802816;
    u16* x1n   = act;                  // NHWC bf16
    u16* x2n   = act + SZ;
    u16* qtb   = act + 2 * SZ;         // NHWC
    u16* ktb   = act + 3 * SZ;         // NHWC
    u16* vbuf  = act + 4 * SZ;         // NCHW
    u16* attnb = act + 5 * SZ;         // NHWC
    float* y1  = (float*)(act + 6 * SZ);  // fp32 NCHW (2*SZ u16)
    u16* y1n   = act + 8 * SZ;         // NHWC
    u16* h1    = act + 9 * SZ;         // NHWC [b][hw][1024], 4*SZ
    u16* h2    = act + 13 * SZ;        // NHWC, 4*SZ

    // weights->bf16 + dw transpose (one launch; independent of activations)
    cvt_all<<<804, 256, 0, stream>>>(q_w, k_w, v_w, proj_w, fc1_w, fc2_w,
                                     dw_w, bp, dwt);
    // x1,x2 -> bn1 -> NHWC bf16 (coefs inline)
    xbn_t_kernel<<<dim3(16, 4, 16), 256, 0, stream>>>(x1, x2, bn1_g, bn1_b,
                                                      bn1_m, bn1_v, x1n, x2n);

    // q,k,v: 128x128 tiles, 8 waves (grid 384); temp folded inline
    qkv_gemm128<<<dim3(8, 6, BATCH), 512, 0, stream>>>(qwb, kwb, vwb, x1n, x2n,
                                                       temp, qtb, ktb, vbuf);

    attn_mfma<<<512, 256, 0, stream>>>(qtb, ktb, vbuf, attnb);

    // y1 = x1 + proj(attn) (fp32 NCHW); y1n = bn2(y1) (bf16 NHWC, coefs inline)
    gemm_nhwc<<<dim3(16, 4, BATCH), 256, 0, stream>>>(pjwb, attnb, proj_b, x1,
                                                      y1, y1n, bn2_g, bn2_b,
                                                      bn2_m, bn2_v, CCH, CCH);
    // h1 = fc1(y1n) + b (bf16 NHWC): 128x128 tiles (grid 512)
    gemm128_nhwc<<<dim3(8, 8, BATCH), 512, 0, stream>>>(fc1wb, y1n, fc1_b, h1,
                                                        CCH, HIDC);
    // h2 = gelu(dw(h1))
    dwgelu_nhwc<<<(BATCH * HW * HIDC / 8) / 256, 256, 0, stream>>>(h1, dwt, h2);

    // out = y1 + fc2(h2) + b (fp32 NCHW)
    gemm_nhwc<<<dim3(16, 4, BATCH), 256, 0, stream>>>(fc2wb, h2, fc2_b, y1,
                                                      (float*)d_out, nullptr,
                                                      nullptr, nullptr, nullptr,
                                                      nullptr, HIDC, CCH);
}

// Round 17
// 106.277 us; speedup vs baseline: 1.1078x; 1.0290x over previous
//
#include <hip/hip_runtime.h>
#include <math.h>

#define HW    1024
#define CCH   256
#define NHEAD 8
#define HIDC  1024
#define BATCH 8
#define L2E   1.44269504f

typedef unsigned short u16;
typedef __attribute__((ext_vector_type(8))) short  bf16x8;
typedef __attribute__((ext_vector_type(4))) float  f32x4;
typedef __attribute__((ext_vector_type(8))) unsigned short us8;
typedef __attribute__((ext_vector_type(4))) unsigned short us4;

__device__ __forceinline__ u16 f2b(float f) {
    union { float f; unsigned u; } c; c.f = f;
    unsigned r = c.u + 0x7FFFu + ((c.u >> 16) & 1u);
    return (u16)(r >> 16);
}
__device__ __forceinline__ float b2f(u16 u) {
    union { unsigned u; float f; } c; c.u = ((unsigned)u) << 16;
    return c.f;
}
// NON-volatile pure value ops: scheduler may reorder/CSE.
__device__ __forceinline__ unsigned cvt_pk_bf16(float a, float b) {
    unsigned r;
    asm("v_cvt_pk_bf16_f32 %0, %1, %2" : "=v"(r) : "v"(a), "v"(b));
    return r;
}
__device__ __forceinline__ float fexp2(float x) {
    float r;
    asm("v_exp_f32 %0, %1" : "=v"(r) : "v"(x));
    return r;
}
__device__ __forceinline__ float frcp(float x) {
    float r;
    asm("v_rcp_f32 %0, %1" : "=v"(r) : "v"(x));
    return r;
}

// ---------------------------------------------------------------------------
// PREP (one launch): weights->bf16, dw transpose, AND x1/x2 bn1->NHWC bf16.
// bid < 768: six GEMM weights; 768..803: dwt; >= 804: xbn transpose tiles.
// ---------------------------------------------------------------------------
__global__ __launch_bounds__(256)
void prep_all(const float* __restrict__ qw, const float* __restrict__ kw,
              const float* __restrict__ vw, const float* __restrict__ pw,
              const float* __restrict__ f1, const float* __restrict__ f2,
              const float* __restrict__ dw,
              const float* __restrict__ x1, const float* __restrict__ x2,
              const float* __restrict__ g1, const float* __restrict__ b1,
              const float* __restrict__ m1, const float* __restrict__ v1,
              u16* __restrict__ dst, u16* __restrict__ dwt,
              u16* __restrict__ o1, u16* __restrict__ o2) {
    __shared__ alignas(16) u16 lt[64 * 72];
    int bid = blockIdx.x;
    int tid = threadIdx.x;
    if (bid < 768) {
        const float* src; size_t off; int lb;
        if      (bid < 64)  { src = qw; off = 0;      lb = bid; }
        else if (bid < 128) { src = kw; off = 65536;  lb = bid - 64; }
        else if (bid < 192) { src = vw; off = 131072; lb = bid - 128; }
        else if (bid < 256) { src = pw; off = 196608; lb = bid - 192; }
        else if (bid < 512) { src = f1; off = 262144; lb = bid - 256; }
        else                { src = f2; off = 524288; lb = bid - 512; }
        int i = lb * 1024 + tid * 4;
        float4 v = *(const float4*)(src + i);
        us4 o = { f2b(v.x), f2b(v.y), f2b(v.z), f2b(v.w) };
        *(us4*)(dst + off + i) = o;
        return;
    }
    if (bid < 804) {
        int idx = (bid - 768) * 256 + tid;
        if (idx < 9 * HIDC) {
            int t = idx >> 10, c = idx & 1023;
            dwt[t * HIDC + c] = f2b(dw[c * 9 + t]);
        }
        return;
    }
    // xbn transpose: flat index over (x=16, y=4, z=16)
    int fi = bid - 804;
    int bx = fi & 15, by = (fi >> 4) & 3, z = fi >> 6;
    const float* x = (z & 1) ? x2 : x1;
    u16* o = (z & 1) ? o2 : o1;
    int b = z >> 1;
    int n0 = bx * 64, c0 = by * 64;
    const float* xb = x + ((size_t)b * CCH + c0) * HW + n0;
    int row = tid >> 4, col4 = (tid & 15) * 4;
#pragma unroll
    for (int it = 0; it < 4; ++it) {
        int rr = it * 16 + row;
        int cch = c0 + rr;
        float sc = g1[cch] * rsqrtf(v1[cch] + 1e-5f);
        float sh = b1[cch] - m1[cch] * sc;
        float4 v = *(const float4*)(xb + (size_t)rr * HW + col4);
        lt[(col4 + 0) * 72 + rr] = f2b(v.x * sc + sh);
        lt[(col4 + 1) * 72 + rr] = f2b(v.y * sc + sh);
        lt[(col4 + 2) * 72 + rr] = f2b(v.z * sc + sh);
        lt[(col4 + 3) * 72 + rr] = f2b(v.w * sc + sh);
    }
    __syncthreads();
    u16* ob = o + ((size_t)b * HW + n0) * CCH + c0;
#pragma unroll
    for (int rep = 0; rep < 2; ++rep) {
        int idx = tid * 2 + rep;
        int nl = idx >> 3, slot = idx & 7;
        us8 v = *(const us8*)(&lt[nl * 72 + slot * 8]);
        *(us8*)(ob + (size_t)nl * CCH + slot * 8) = v;
    }
}

// ---------------------------------------------------------------------------
// Shared staging: rule-21 gload_lds pair (linear LDS dest, inverse-swizzled
// source). Works for any wave id wv (region = wv*2+r spans 8 rows each).
// ---------------------------------------------------------------------------
__device__ __forceinline__ void stage_pair(const u16* Xb, const u16* Wb, int K, int koff,
                                           u16* lx, u16* lw, int wv, int lane) {
    int rl = lane >> 3, slot = lane & 7;
#pragma unroll
    for (int r = 0; r < 2; ++r) {
        int region = wv * 2 + r;
        int row = region * 8 + rl;
        int sw = ((slot ^ (row & 7)) << 3) + koff;
        __builtin_amdgcn_global_load_lds(
            (const __attribute__((address_space(1))) void*)(Xb + (size_t)row * K + sw),
            (__attribute__((address_space(3))) void*)(lx + (region << 9)), 16, 0, 0);
        __builtin_amdgcn_global_load_lds(
            (const __attribute__((address_space(1))) void*)(Wb + (size_t)row * K + sw),
            (__attribute__((address_space(3))) void*)(lw + (region << 9)), 16, 0, 0);
    }
}

__device__ __forceinline__ void compute_tile(const u16* lx, const u16* lw,
                                             int cc, int g, int wr, int wc,
                                             f32x4 acc[2][2]) {
#pragma unroll
    for (int ks = 0; ks < 2; ++ks) {
        bf16x8 ax[2], bw[2];
#pragma unroll
        for (int mi = 0; mi < 2; ++mi) {
            int row = wr * 32 + mi * 16 + cc;
            int ck = (ks * 4 + g) ^ (row & 7);
            ax[mi] = *(const bf16x8*)(lx + row * 64 + ck * 8);
        }
#pragma unroll
        for (int ni = 0; ni < 2; ++ni) {
            int row = wc * 32 + ni * 16 + cc;
            int ck = (ks * 4 + g) ^ (row & 7);
            bw[ni] = *(const bf16x8*)(lw + row * 64 + ck * 8);
        }
#pragma unroll
        for (int mi = 0; mi < 2; ++mi)
#pragma unroll
            for (int ni = 0; ni < 2; ++ni)
                acc[mi][ni] = __builtin_amdgcn_mfma_f32_16x16x32_bf16(
                    ax[mi], bw[ni], acc[mi][ni], 0, 0, 0);
    }
}

// 128x128-tile compute: 8 waves, wave tile 64(n) x 32(m): 4x2 fragments.
__device__ __forceinline__ void compute_tile128(const u16* lx, const u16* lw,
                                                int cc, int g, int wr, int wcq,
                                                f32x4 acc[4][2]) {
#pragma unroll
    for (int ks = 0; ks < 2; ++ks) {
        bf16x8 ax[4], bw[2];
#pragma unroll
        for (int mi = 0; mi < 4; ++mi) {
            int row = wr * 64 + mi * 16 + cc;
            int ck = (ks * 4 + g) ^ (row & 7);
            ax[mi] = *(const bf16x8*)(lx + row * 64 + ck * 8);
        }
#pragma unroll
        for (int ni = 0; ni < 2; ++ni) {
            int row = wcq * 32 + ni * 16 + cc;
            int ck = (ks * 4 + g) ^ (row & 7);
            bw[ni] = *(const bf16x8*)(lw + row * 64 + ck * 8);
        }
#pragma unroll
        for (int mi = 0; mi < 4; ++mi)
#pragma unroll
            for (int ni = 0; ni < 2; ++ni)
                acc[mi][ni] = __builtin_amdgcn_mfma_f32_16x16x32_bf16(
                    ax[mi], bw[ni], acc[mi][ni], 0, 0, 0);
    }
}

// ---------------------------------------------------------------------------
// Generic 64x64 GEMM (proj / fc2). X NHWC [b][HW][K]; W [M][K].
// outf/resid fp32 NCHW; outb bf16 NHWC. BN2 coefs computed INLINE.
// ---------------------------------------------------------------------------
__global__ __launch_bounds__(256, 4)
void gemm_nhwc(const u16* __restrict__ W, const u16* __restrict__ X,
               const float* __restrict__ bias, const float* __restrict__ resid,
               float* __restrict__ outf, u16* __restrict__ outb,
               const float* __restrict__ bn_g, const float* __restrict__ bn_b,
               const float* __restrict__ bn_m, const float* __restrict__ bn_v,
               int K, int M) {
    __shared__ alignas(16) u16 lx[2][4096];
    __shared__ alignas(16) u16 lw[2][4096];
    const int tid = threadIdx.x, l = tid & 63, wv = tid >> 6;
    const int cc = l & 15, g = l >> 4;
    const int wr = wv >> 1, wc = wv & 1;
    const int n0 = blockIdx.x * 64, m0 = blockIdx.y * 64, b = blockIdx.z;
    const u16* Xb = X + ((size_t)b * HW + n0) * K;
    const u16* Wb = W + (size_t)m0 * K;
    const size_t bo = (size_t)b * M * HW;
    if (resid) resid += bo;
    if (outf)  outf  += bo;
    if (outb)  outb  += (size_t)b * HW * M;

    f32x4 acc[2][2];
    acc[0][0] = (f32x4)0.f; acc[0][1] = (f32x4)0.f;
    acc[1][0] = (f32x4)0.f; acc[1][1] = (f32x4)0.f;

    const int NT = K >> 6;
    stage_pair(Xb, Wb, K, 0, lx[0], lw[0], wv, l);
    __syncthreads();
    int cur = 0;
    for (int t = 0; t < NT; ++t) {
        if (t + 1 < NT)
            stage_pair(Xb, Wb, K, (t + 1) * 64, lx[cur ^ 1], lw[cur ^ 1], wv, l);
        compute_tile(lx[cur], lw[cur], cc, g, wr, wc, acc);
        __syncthreads();
        cur ^= 1;
    }

#pragma unroll
    for (int mi = 0; mi < 2; ++mi)
#pragma unroll
        for (int ni = 0; ni < 2; ++ni) {
            int m  = m0 + wc * 32 + ni * 16 + cc;
            int nb = n0 + wr * 32 + mi * 16 + g * 4;
            f32x4 v = acc[mi][ni];
            if (bias) { float bv = bias[m]; v[0] += bv; v[1] += bv; v[2] += bv; v[3] += bv; }
            if (resid) {
                float4 rv = *(const float4*)(resid + (size_t)m * HW + nb);
                v[0] += rv.x; v[1] += rv.y; v[2] += rv.z; v[3] += rv.w;
            }
            if (outf) *(f32x4*)(outf + (size_t)m * HW + nb) = v;
            if (outb) {
                float sa = 1.0f, sb = 0.0f;
                if (bn_g) {
                    sa = bn_g[m] * rsqrtf(bn_v[m] + 1e-5f);
                    sb = bn_b[m] - bn_m[m] * sa;
                }
#pragma unroll
                for (int r = 0; r < 4; ++r)
                    outb[(size_t)(nb + r) * M + m] = f2b(v[r] * sa + sb);
            }
        }
}

// ---------------------------------------------------------------------------
// fc1: 128x128-tile GEMM (8 waves), bias + bf16 NHWC out. K=256, M=1024.
// ---------------------------------------------------------------------------
__global__ __launch_bounds__(512, 4)
void gemm128_nhwc(const u16* __restrict__ W, const u16* __restrict__ X,
                  const float* __restrict__ bias, u16* __restrict__ outb,
                  int K, int M) {
    __shared__ alignas(16) u16 lx[2][8192];
    __shared__ alignas(16) u16 lw[2][8192];
    const int tid = threadIdx.x, l = tid & 63, wv = tid >> 6;
    const int cc = l & 15, g = l >> 4;
    const int wr = wv >> 2, wcq = wv & 3;
    const int n0 = blockIdx.x * 128, m0 = blockIdx.y * 128, b = blockIdx.z;
    const u16* Xb = X + ((size_t)b * HW + n0) * K;
    const u16* Wb = W + (size_t)m0 * K;
    outb += (size_t)b * HW * M;

    f32x4 acc[4][2];
#pragma unroll
    for (int i = 0; i < 4; ++i) { acc[i][0] = (f32x4)0.f; acc[i][1] = (f32x4)0.f; }

    const int NT = K >> 6;
    stage_pair(Xb, Wb, K, 0, lx[0], lw[0], wv, l);
    __syncthreads();
    int cur = 0;
    for (int t = 0; t < NT; ++t) {
        if (t + 1 < NT)
            stage_pair(Xb, Wb, K, (t + 1) * 64, lx[cur ^ 1], lw[cur ^ 1], wv, l);
        compute_tile128(lx[cur], lw[cur], cc, g, wr, wcq, acc);
        __syncthreads();
        cur ^= 1;
    }

#pragma unroll
    for (int mi = 0; mi < 4; ++mi)
#pragma unroll
        for (int ni = 0; ni < 2; ++ni) {
            int m  = m0 + wcq * 32 + ni * 16 + cc;
            int nb = n0 + wr * 64 + mi * 16 + g * 4;
            float bv = bias[m];
#pragma unroll
            for (int r = 0; r < 4; ++r)
                outb[(size_t)(nb + r) * M + m] = f2b(acc[mi][ni][r] + bv);
        }
}

// ---------------------------------------------------------------------------
// QKV GEMM, 128x128 tiles, 8 waves. sel = y>>1 (0=Q,1=K,2=V), m0=(y&1)*128.
// Q scaled inline by temp[m>>5]*log2e. Q,K -> NHWC; V -> NCHW.
// ---------------------------------------------------------------------------
__global__ __launch_bounds__(512, 4)
void qkv_gemm128(const u16* __restrict__ wq, const u16* __restrict__ wk,
                 const u16* __restrict__ wv, const u16* __restrict__ x1n,
                 const u16* __restrict__ x2n, const float* __restrict__ temp,
                 u16* __restrict__ qt, u16* __restrict__ kt, u16* __restrict__ vbuf) {
    __shared__ alignas(16) u16 lx[2][8192];
    __shared__ alignas(16) u16 lw[2][8192];
    const int tid = threadIdx.x, l = tid & 63, wvv = tid >> 6;
    const int cc = l & 15, g = l >> 4;
    const int wr = wvv >> 2, wcq = wvv & 3;
    const int sel = blockIdx.y >> 1;
    const int n0 = blockIdx.x * 128, m0 = (blockIdx.y & 1) * 128, b = blockIdx.z;
    const u16* W = (sel == 0) ? wq : (sel == 1) ? wk : wv;
    const u16* Xb = ((sel == 0) ? x1n : x2n) + ((size_t)b * HW + n0) * CCH;
    const u16* Wb = W + (size_t)m0 * CCH;

    f32x4 acc[4][2];
#pragma unroll
    for (int i = 0; i < 4; ++i) { acc[i][0] = (f32x4)0.f; acc[i][1] = (f32x4)0.f; }

    stage_pair(Xb, Wb, CCH, 0, lx[0], lw[0], wvv, l);
    __syncthreads();
    int cur = 0;
    for (int t = 0; t < 4; ++t) {
        if (t + 1 < 4)
            stage_pair(Xb, Wb, CCH, (t + 1) * 64, lx[cur ^ 1], lw[cur ^ 1], wvv, l);
        compute_tile128(lx[cur], lw[cur], cc, g, wr, wcq, acc);
        __syncthreads();
        cur ^= 1;
    }

    if (sel < 2) {
        u16* ob = ((sel == 0) ? qt : kt) + (size_t)b * HW * CCH;
#pragma unroll
        for (int mi = 0; mi < 4; ++mi)
#pragma unroll
            for (int ni = 0; ni < 2; ++ni) {
                int m  = m0 + wcq * 32 + ni * 16 + cc;
                int nb = n0 + wr * 64 + mi * 16 + g * 4;
                float sc = (sel == 0) ? temp[m >> 5] * L2E : 1.0f;
#pragma unroll
                for (int r = 0; r < 4; ++r)
                    ob[(size_t)(nb + r) * CCH + m] = f2b(acc[mi][ni][r] * sc);
            }
    } else {
        u16* ob = vbuf + (size_t)b * CCH * HW;
#pragma unroll
        for (int mi = 0; mi < 4; ++mi)
#pragma unroll
            for (int ni = 0; ni < 2; ++ni) {
                int m  = m0 + wcq * 32 + ni * 16 + cc;
                int nb = n0 + wr * 64 + mi * 16 + g * 4;
                us4 ov = { f2b(acc[mi][ni][0]), f2b(acc[mi][ni][1]),
                           f2b(acc[mi][ni][2]), f2b(acc[mi][ni][3]) };
                *(us4*)(ob + (size_t)m * HW + nb) = ov;
            }
    }
}

// ---------------------------------------------------------------------------
// Flash attention (converged config): max-free softmax, raw v_exp,
// 256-thread blocks (4 waves x 32 q-rows, QBLK=128), grid 512 XCD-local.
// ---------------------------------------------------------------------------
#define ATT_LOAD(K0, K1, K2, K3, V0, V1, V2, V3, T) do {                      \
    const int j0_ = (T) * 64;                                                 \
    K0 = *(const bf16x8*)(kb + (size_t)(j0_ +  0 + c) * CCH + g * 8);         \
    K1 = *(const bf16x8*)(kb + (size_t)(j0_ + 16 + c) * CCH + g * 8);         \
    K2 = *(const bf16x8*)(kb + (size_t)(j0_ + 32 + c) * CCH + g * 8);         \
    K3 = *(const bf16x8*)(kb + (size_t)(j0_ + 48 + c) * CCH + g * 8);         \
    V0 = *(const bf16x8*)(vb + (size_t)( 0 + c) * HW + j0_ +  0 + g * 8);     \
    V1 = *(const bf16x8*)(vb + (size_t)(16 + c) * HW + j0_ +  0 + g * 8);     \
    V2 = *(const bf16x8*)(vb + (size_t)( 0 + c) * HW + j0_ + 32 + g * 8);     \
    V3 = *(const bf16x8*)(vb + (size_t)(16 + c) * HW + j0_ + 32 + g * 8);     \
} while (0)

#define ATT_COMP(K0, K1, K2, K3, V0, V1, V2, V3) do {                         \
    f32x4 s0[4], s1[4];                                                       \
    __builtin_amdgcn_s_setprio(1);                                            \
    s0[0] = __builtin_amdgcn_mfma_f32_16x16x32_bf16(K0, qf0, (f32x4)0.f, 0, 0, 0); \
    s1[0] = __builtin_amdgcn_mfma_f32_16x16x32_bf16(K0, qf1, (f32x4)0.f, 0, 0, 0); \
    s0[1] = __builtin_amdgcn_mfma_f32_16x16x32_bf16(K1, qf0, (f32x4)0.f, 0, 0, 0); \
    s1[1] = __builtin_amdgcn_mfma_f32_16x16x32_bf16(K1, qf1, (f32x4)0.f, 0, 0, 0); \
    s0[2] = __builtin_amdgcn_mfma_f32_16x16x32_bf16(K2, qf0, (f32x4)0.f, 0, 0, 0); \
    s1[2] = __builtin_amdgcn_mfma_f32_16x16x32_bf16(K2, qf1, (f32x4)0.f, 0, 0, 0); \
    s0[3] = __builtin_amdgcn_mfma_f32_16x16x32_bf16(K3, qf0, (f32x4)0.f, 0, 0, 0); \
    s1[3] = __builtin_amdgcn_mfma_f32_16x16x32_bf16(K3, qf1, (f32x4)0.f, 0, 0, 0); \
    __builtin_amdgcn_s_setprio(0);                                            \
    float ps0 = 0.f, ps1 = 0.f;                                               \
    _Pragma("unroll")                                                         \
    for (int nj = 0; nj < 4; ++nj) {                                          \
        int ck = (2 * nj + (g >> 1)) ^ swz;                                   \
        float a0 = fexp2(s0[nj][0]), a1 = fexp2(s0[nj][1]);                   \
        float a2 = fexp2(s0[nj][2]), a3 = fexp2(s0[nj][3]);                   \
        ps0 += (a0 + a1) + (a2 + a3);                                         \
        uint2 pk0;                                                            \
        pk0.x = cvt_pk_bf16(a0, a1);                                          \
        pk0.y = cvt_pk_bf16(a2, a3);                                          \
        *(uint2*)(&P[c * 64 + ck * 8 + (g & 1) * 4]) = pk0;                   \
        float d0 = fexp2(s1[nj][0]), d1 = fexp2(s1[nj][1]);                   \
        float d2 = fexp2(s1[nj][2]), d3 = fexp2(s1[nj][3]);                   \
        ps1 += (d0 + d1) + (d2 + d3);                                         \
        uint2 pk1;                                                            \
        pk1.x = cvt_pk_bf16(d0, d1);                                          \
        pk1.y = cvt_pk_bf16(d2, d3);                                          \
        *(uint2*)(&P[(16 + c) * 64 + ck * 8 + (g & 1) * 4]) = pk1;            \
    }                                                                         \
    rl0 += ps0; rl1 += ps1;                                                   \
    __builtin_amdgcn_s_setprio(1);                                            \
    _Pragma("unroll")                                                         \
    for (int kj = 0; kj < 2; ++kj) {                                          \
        bf16x8 pf0 = *(const bf16x8*)(&P[c * 64 + ((kj * 4 + g) ^ swz) * 8]); \
        bf16x8 pf1 = *(const bf16x8*)(&P[(16 + c) * 64 + ((kj * 4 + g) ^ swz) * 8]); \
        o00 = __builtin_amdgcn_mfma_f32_16x16x32_bf16(pf0, (kj ? V2 : V0), o00, 0, 0, 0); \
        o01 = __builtin_amdgcn_mfma_f32_16x16x32_bf16(pf0, (kj ? V3 : V1), o01, 0, 0, 0); \
        o10 = __builtin_amdgcn_mfma_f32_16x16x32_bf16(pf1, (kj ? V2 : V0), o10, 0, 0, 0); \
        o11 = __builtin_amdgcn_mfma_f32_16x16x32_bf16(pf1, (kj ? V3 : V1), o11, 0, 0, 0); \
    }                                                                         \
    __builtin_amdgcn_s_setprio(0);                                            \
} while (0)

__global__ __launch_bounds__(256)
void attn_mfma(const u16* __restrict__ qt, const u16* __restrict__ kt,
               const u16* __restrict__ vv, u16* __restrict__ out) {
    __shared__ alignas(16) u16 lds[8192];   // 4 waves x 2KB P buffers
    const int tid = threadIdx.x, l = tid & 63, w = tid >> 6;
    const int c = l & 15, g = l >> 4;
    const int swz = (c & 7) ^ ((c & 8) >> 1);
    const int bh = blockIdx.x & 63, qx = blockIdx.x >> 6;
    const int b = bh >> 3, h = bh & 7;
    const int n0 = qx * 128;
    u16* P = lds + w * 2048;

    const u16* qb = qt + ((size_t)b * HW + n0 + w * 32) * CCH + h * 32;
    const u16* kb = kt + (size_t)b * HW * CCH + h * 32;
    const u16* vb = vv + ((size_t)b * CCH + h * 32) * HW;

    bf16x8 qf0 = *(const bf16x8*)(qb + (size_t)c * CCH + g * 8);
    bf16x8 qf1 = *(const bf16x8*)(qb + (size_t)(16 + c) * CCH + g * 8);

    float rl0 = 0.f, rl1 = 0.f;
    f32x4 o00 = (f32x4)0.f, o01 = (f32x4)0.f;
    f32x4 o10 = (f32x4)0.f, o11 = (f32x4)0.f;

    bf16x8 kA0, kA1, kA2, kA3, vA0, vA1, vA2, vA3;
    bf16x8 kB0, kB1, kB2, kB3, vB0, vB1, vB2, vB3;

    ATT_LOAD(kA0, kA1, kA2, kA3, vA0, vA1, vA2, vA3, 0);
#pragma unroll 1
    for (int t = 0; t < 16; t += 2) {
        ATT_LOAD(kB0, kB1, kB2, kB3, vB0, vB1, vB2, vB3, t + 1);
        ATT_COMP(kA0, kA1, kA2, kA3, vA0, vA1, vA2, vA3);
        if (t + 2 < 16)
            ATT_LOAD(kA0, kA1, kA2, kA3, vA0, vA1, vA2, vA3, t + 2);
        ATT_COMP(kB0, kB1, kB2, kB3, vB0, vB1, vB2, vB3);
    }

    rl0 += __shfl_xor(rl0, 16); rl0 += __shfl_xor(rl0, 32);
    rl1 += __shfl_xor(rl1, 16); rl1 += __shfl_xor(rl1, 32);
    float inv0 = 1.0f / rl0, inv1 = 1.0f / rl1;
    float invr0[4], invr1[4];
#pragma unroll
    for (int r = 0; r < 4; ++r) {
        int src = (l & 48) | (g * 4 + r);
        invr0[r] = __shfl(inv0, src);
        invr1[r] = __shfl(inv1, src);
    }
    // O staging to wave-private LDS (plain C++: aliasing keeps order)
#pragma unroll
    for (int r = 0; r < 4; ++r) {
        int row0 = g * 4 + r, row1 = 16 + g * 4 + r;
        P[row0 * 40 + c]      = f2b(o00[r] * invr0[r]);
        P[row0 * 40 + 16 + c] = f2b(o01[r] * invr0[r]);
        P[row1 * 40 + c]      = f2b(o10[r] * invr1[r]);
        P[row1 * 40 + 16 + c] = f2b(o11[r] * invr1[r]);
    }
#pragma unroll
    for (int rep = 0; rep < 2; ++rep) {
        int u = l * 2 + rep;
        int i = u >> 2, part = u & 3;
        us8 ov = *(const us8*)(&P[i * 40 + part * 8]);
        *(us8*)(out + ((size_t)b * HW + n0 + w * 32 + i) * CCH + h * 32 + part * 8) = ov;
    }
}

// ---------------------------------------------------------------------------
// Depthwise 3x3 (SAME) + tanh-form GELU via sigmoid. NHWC bf16, 8 ch/thread.
// ---------------------------------------------------------------------------
__global__ __launch_bounds__(256)
void dwgelu_nhwc(const u16* __restrict__ in, const u16* __restrict__ wt,
                 u16* __restrict__ out) {
    int gid = blockIdx.x * 256 + threadIdx.x;
    int c0 = (gid & 127) * 8;
    int sp = (gid >> 7) & 1023;
    int b  = gid >> 17;
    int y = sp >> 5, x = sp & 31;
    const u16* ip = in + (size_t)b * HW * HIDC;
    float acc[8] = {0.f, 0.f, 0.f, 0.f, 0.f, 0.f, 0.f, 0.f};
#pragma unroll
    for (int dy = -1; dy <= 1; ++dy) {
        int yy = y + dy;
        if ((unsigned)yy >= 32u) continue;
#pragma unroll
        for (int dx = -1; dx <= 1; ++dx) {
            int xx = x + dx;
            if ((unsigned)xx >= 32u) continue;
            us8 iv = *(const us8*)(ip + (size_t)(yy * 32 + xx) * HIDC + c0);
            us8 wv = *(const us8*)(wt + ((dy + 1) * 3 + dx + 1) * HIDC + c0);
#pragma unroll
            for (int e = 0; e < 8; ++e)
                acc[e] = fmaf(b2f(wv[e]), b2f(iv[e]), acc[e]);
        }
    }
    us8 o;
#pragma unroll
    for (int e = 0; e < 8; ++e) {
        float v  = acc[e];
        float p  = fmaf(v * v, 0.044715f, 1.0f);
        float ar = (-2.3021178f * v) * p;
        float ge = v * frcp(1.0f + fexp2(ar));
        o[e] = f2b(ge);
    }
    *(us8*)(out + (size_t)gid * 8) = o;
}

// ---------------------------------------------------------------------------
extern "C" void kernel_launch(void* const* d_in, const int* in_sizes, int n_in,
                              void* d_out, int out_size, void* d_ws, size_t ws_size,
                              hipStream_t stream) {
    const float* x1     = (const float*)d_in[0];
    const float* x2     = (const float*)d_in[1];
    const float* bn1_g  = (const float*)d_in[2];
    const float* bn1_b  = (const float*)d_in[3];
    const float* bn1_m  = (const float*)d_in[4];
    const float* bn1_v  = (const float*)d_in[5];
    const float* q_w    = (const float*)d_in[6];
    const float* k_w    = (const float*)d_in[7];
    const float* v_w    = (const float*)d_in[8];
    const float* temp   = (const float*)d_in[9];
    const float* proj_w = (const float*)d_in[10];
    const float* proj_b = (const float*)d_in[11];
    const float* bn2_g  = (const float*)d_in[12];
    const float* bn2_b  = (const float*)d_in[13];
    const float* bn2_m  = (const float*)d_in[14];
    const float* bn2_v  = (const float*)d_in[15];
    const float* fc1_w  = (const float*)d_in[16];
    const float* fc1_b  = (const float*)d_in[17];
    const float* dw_w   = (const float*)d_in[18];
    const float* fc2_w  = (const float*)d_in[19];
    const float* fc2_b  = (const float*)d_in[20];

    const size_t SZ = (size_t)BATCH * CCH * HW;   // 2,097,152 elems
    u16* bp    = (u16*)d_ws;
    u16* qwb   = bp;
    u16* kwb   = bp + 65536;
    u16* vwb   = bp + 131072;
    u16* pjwb  = bp + 196608;
    u16* fc1wb = bp + 262144;
    u16* fc2wb = bp + 524288;
    u16* dwt   = bp + 786432;          // 9216, reserve 16384
    u16* act   = bp + 802816;
    u16* x1n   = act;                  // NHWC bf16
    u16* x2n   = act + SZ;
    u16* qtb   = act + 2 * SZ;         // NHWC
    u16* ktb   = act + 3 * SZ;         // NHWC
    u16* vbuf  = act + 4 * SZ;         // NCHW
    u16* attnb = act + 5 * SZ;         // NHWC
    float* y1  = (float*)(act + 6 * SZ);  // fp32 NCHW (2*SZ u16)
    u16* y1n   = act + 8 * SZ;         // NHWC
    u16* h1    = act + 9 * SZ;         // NHWC [b][hw][1024], 4*SZ
    u16* h2    = act + 13 * SZ;        // NHWC, 4*SZ

    // ONE prep launch: weights->bf16, dwt, bn1(x1,x2)->NHWC bf16
    prep_all<<<1828, 256, 0, stream>>>(q_w, k_w, v_w, proj_w, fc1_w, fc2_w,
                                       dw_w, x1, x2, bn1_g, bn1_b, bn1_m,
                                       bn1_v, bp, dwt, x1n, x2n);

    // q,k,v: 128x128 tiles, 8 waves (grid 384); temp folded inline
    qkv_gemm128<<<dim3(8, 6, BATCH), 512, 0, stream>>>(qwb, kwb, vwb, x1n, x2n,
                                                       temp, qtb, ktb, vbuf);

    attn_mfma<<<512, 256, 0, stream>>>(qtb, ktb, vbuf, attnb);

    // y1 = x1 + proj(attn) (fp32 NCHW); y1n = bn2(y1) (bf16 NHWC, coefs inline)
    gemm_nhwc<<<dim3(16, 4, BATCH), 256, 0, stream>>>(pjwb, attnb, proj_b, x1,
                                                      y1, y1n, bn2_g, bn2_b,
                                                      bn2_m, bn2_v, CCH, CCH);
    // h1 = fc1(y1n) + b (bf16 NHWC): 128x128 tiles (grid 512)
    gemm128_nhwc<<<dim3(8, 8, BATCH), 512, 0, stream>>>(fc1wb, y1n, fc1_b, h1,
                                                        CCH, HIDC);
    // h2 = gelu(dw(h1))
    dwgelu_nhwc<<<(BATCH * HW * HIDC / 8) / 256, 256, 0, stream>>>(h1, dwt, h2);

    // out = y1 + fc2(h2) + b (fp32 NCHW)
    gemm_nhwc<<<dim3(16, 4, BATCH), 256, 0, stream>>>(fc2wb, h2, fc2_b, y1,
                                                      (float*)d_out, nullptr,
                                                      nullptr, nullptr, nullptr,
                                                      nullptr, HIDC, CCH);
}